// Round 1
// baseline (2842.551 us; speedup 1.0000x reference)
//
#include <hip/hip_runtime.h>
#include <math.h>

#define NLEV 12
#define B_LINES 4096
#define P_PTS 1000

// Per-level table layout, mirrors _level_specs() exactly (computed host-side
// with the same double-precision pow/ceil arithmetic as numpy).
struct LevelSpec {
    unsigned off;    // entry offset into table ([T,2] rows)
    unsigned mask;   // params-1 (power-of-2 for hash levels; unused for dense)
    float    scale;  // BASE_RES * f^l - 1
    unsigned R;      // res + 1 (dense stride base)
};
struct Specs { LevelSpec L[NLEV]; };

static void compute_specs(int D, Specs* sp) {
    double f = pow(8192.0 / 16.0, 1.0 / 11.0);
    unsigned offset = 0;
    for (int l = 0; l < NLEV; ++l) {
        double scale = 16.0 * pow(f, (double)l) - 1.0;
        int res = (int)ceil(scale) + 1;
        unsigned long long dense = 1ull;
        for (int d = 0; d < D; ++d) dense *= (unsigned long long)(res + 1);
        unsigned long long params = dense > (1ull << 21) ? (1ull << 21) : dense;
        params = ((params + 7ull) / 8ull) * 8ull;
        sp->L[l].off   = offset;
        sp->L[l].mask  = (unsigned)params - 1u;
        sp->L[l].scale = (float)scale;
        sp->L[l].R     = (unsigned)(res + 1);
        offset += (unsigned)params;
    }
}

// ---------------------------------------------------------------------------

__device__ __forceinline__ float block_reduce_256(float v) {
    __shared__ float red[256];
    int tid = threadIdx.x;
    red[tid] = v;
    __syncthreads();
    #pragma unroll
    for (int s = 128; s >= 1; s >>= 1) {
        if (tid < s) red[tid] += red[tid + s];
        __syncthreads();
    }
    return red[0];
}

// MLP 24 -> 64(relu) -> 1. Weights are wave-uniform (kernel-arg pointers,
// compile-time indices) -> backend scalarizes to s_load; inner loop is
// v_fmac with SGPR operand. h kept in two 32-reg halves to limit VGPR.
__device__ __forceinline__ float mlp_24_64_1(const float feat[24],
        const float* __restrict__ w1, const float* __restrict__ b1,
        const float* __restrict__ w2, const float* __restrict__ b2) {
    float o = b2[0];
    #pragma unroll
    for (int half = 0; half < 2; ++half) {
        float h[32];
        #pragma unroll
        for (int j = 0; j < 32; ++j) h[j] = b1[half * 32 + j];
        #pragma unroll
        for (int k = 0; k < 24; ++k) {
            float fv = feat[k];
            #pragma unroll
            for (int j = 0; j < 32; ++j)
                h[j] = fmaf(fv, w1[k * 64 + half * 32 + j], h[j]);
        }
        #pragma unroll
        for (int j = 0; j < 32; ++j)
            o = fmaf(fmaxf(h[j], 0.f), w2[half * 32 + j], o);
    }
    return o;
}

// 3D grid encode for one point (x already in [0,1] domain: x01).
__device__ __forceinline__ void encode3(float x0, float x1, float x2,
        const float2* __restrict__ tab, const Specs& sp, float feat[24]) {
    #pragma unroll
    for (int l = 0; l < NLEV; ++l) {
        const unsigned off = sp.L[l].off;
        const float scale = sp.L[l].scale;
        float p0 = x0 * scale + 0.5f;
        float p1 = x1 * scale + 0.5f;
        float p2 = x2 * scale + 0.5f;
        float f0 = floorf(p0), f1 = floorf(p1), f2 = floorf(p2);
        float r0 = p0 - f0, r1 = p1 - f1, r2 = p2 - f2;
        float u0 = 1.f - r0, u1 = 1.f - r1, u2 = 1.f - r2;
        unsigned g0 = (unsigned)f0, g1 = (unsigned)f1, g2 = (unsigned)f2;
        unsigned idxs[8];
        if (l >= 4) {  // hash levels for D=3 (dense (res+1)^3 > 2^21 from l=4)
            const unsigned mask = sp.L[l].mask;
            unsigned a1 = g1 * 2654435761u, bb1 = a1 + 2654435761u;
            unsigned a2 = g2 * 805459861u,  bb2 = a2 + 805459861u;
            #pragma unroll
            for (int c = 0; c < 8; ++c) {
                unsigned h = ((c & 1) ? (g0 + 1u) : g0)
                           ^ ((c & 2) ? bb1 : a1)
                           ^ ((c & 4) ? bb2 : a2);
                idxs[c] = h & mask;
            }
        } else {
            const unsigned R = sp.L[l].R;
            unsigned a1 = g1 * R, bb1 = a1 + R;
            unsigned R2 = R * R;
            unsigned a2 = g2 * R2, bb2 = a2 + R2;
            #pragma unroll
            for (int c = 0; c < 8; ++c)
                idxs[c] = ((c & 1) ? (g0 + 1u) : g0)
                        + ((c & 2) ? bb1 : a1)
                        + ((c & 4) ? bb2 : a2);
        }
        float acc0 = 0.f, acc1 = 0.f;
        #pragma unroll
        for (int c = 0; c < 8; ++c) {
            float2 t = tab[off + idxs[c]];
            float w = ((c & 1) ? r0 : u0) * ((c & 2) ? r1 : u1) * ((c & 4) ? r2 : u2);
            acc0 += w * t.x;
            acc1 += w * t.y;
        }
        feat[2 * l]     = acc0;
        feat[2 * l + 1] = acc1;
    }
}

// ---------------------------------------------------------------------------
// Kernel A: one block per line; per-line weighted sum of |opacity - gt|.
__global__ void __launch_bounds__(256) opacity_kernel(
        const float* __restrict__ pts,      // [B*P, 3]
        const float* __restrict__ gt,       // [B*P]
        const float2* __restrict__ tab,     // [tot3, 2]
        const float* __restrict__ w1, const float* __restrict__ b1,
        const float* __restrict__ w2, const float* __restrict__ b2,
        float* __restrict__ S,              // [B] per-line sums
        Specs sp) {
    const int b = blockIdx.x;
    const int tid = threadIdx.x;
    float lsum = 0.f;
    for (int p = tid; p < P_PTS; p += 256) {
        const int i = b * P_PTS + p;
        float x0 = (pts[3 * i + 0] + 1.f) * 0.5f;
        float x1 = (pts[3 * i + 1] + 1.f) * 0.5f;
        float x2 = (pts[3 * i + 2] + 1.f) * 0.5f;
        float feat[24];
        encode3(x0, x1, x2, tab, sp, feat);
        float op = mlp_24_64_1(feat, w1, b1, w2, b2);
        float cw = (p < 500) ? (float)(4.0 / 3.0) : (float)(2.0 / 3.0);
        lsum += fabsf(op - gt[i]) * cw;
    }
    float tot = block_reduce_256(lsum);
    if (tid == 0) S[b] = tot;
}

// Kernel B: one thread per line -> confidence + loss term; per-block partials.
__global__ void __launch_bounds__(256) conf_kernel(
        const float* __restrict__ line,     // [B, 2]
        const float2* __restrict__ tab,     // [tot2, 2]
        const float* __restrict__ w1, const float* __restrict__ b1,
        const float* __restrict__ w2, const float* __restrict__ b2,
        const float* __restrict__ S,        // [B]
        float* __restrict__ partial,        // [16]
        Specs sp) {
    const int b = blockIdx.x * 256 + threadIdx.x;   // grid 16*256 == 4096 exact
    float x0 = (line[2 * b + 0] + 1.f) * 0.5f;
    float x1 = (line[2 * b + 1] + 1.f) * 0.5f;
    float feat[24];
    #pragma unroll
    for (int l = 0; l < NLEV; ++l) {
        const unsigned off = sp.L[l].off;
        const float scale = sp.L[l].scale;
        float p0 = x0 * scale + 0.5f;
        float p1 = x1 * scale + 0.5f;
        float f0 = floorf(p0), f1 = floorf(p1);
        float r0 = p0 - f0, r1 = p1 - f1;
        float u0 = 1.f - r0, u1 = 1.f - r1;
        unsigned g0 = (unsigned)f0, g1 = (unsigned)f1;
        unsigned idx0, idx1, idx2, idx3;
        if (l >= 8) {  // hash levels for D=2 ((res+1)^2 > 2^21 from l=8)
            const unsigned mask = sp.L[l].mask;
            unsigned a1 = g1 * 2654435761u, bb1 = a1 + 2654435761u;
            idx0 = (g0 ^ a1) & mask;
            idx1 = ((g0 + 1u) ^ a1) & mask;
            idx2 = (g0 ^ bb1) & mask;
            idx3 = ((g0 + 1u) ^ bb1) & mask;
        } else {
            const unsigned R = sp.L[l].R;
            unsigned a1 = g1 * R, bb1 = a1 + R;
            idx0 = g0 + a1;
            idx1 = g0 + 1u + a1;
            idx2 = g0 + bb1;
            idx3 = g0 + 1u + bb1;
        }
        float2 t0 = tab[off + idx0], t1 = tab[off + idx1];
        float2 t2 = tab[off + idx2], t3 = tab[off + idx3];
        float w0 = u0 * u1, w1c = r0 * u1, w2c = u0 * r1, w3 = r0 * r1;
        feat[2 * l]     = w0 * t0.x + w1c * t1.x + w2c * t2.x + w3 * t3.x;
        feat[2 * l + 1] = w0 * t0.y + w1c * t1.y + w2c * t2.y + w3 * t3.y;
    }
    float conf = mlp_24_64_1(feat, w1, b1, w2, b2);
    float term = expf(-conf) * (S[b] * (1.0f / (float)P_PTS)) + conf;
    float tot = block_reduce_256(term);
    if (threadIdx.x == 0) partial[blockIdx.x] = tot;
}

__global__ void final_kernel(const float* __restrict__ partial,
                             float* __restrict__ out) {
    if (threadIdx.x == 0) {
        float s = 0.f;
        for (int i = 0; i < 16; ++i) s += partial[i];
        out[0] = s * (1.0f / (float)B_LINES);
    }
}

// ---------------------------------------------------------------------------

extern "C" void kernel_launch(void* const* d_in, const int* in_sizes, int n_in,
                              void* d_out, int out_size, void* d_ws, size_t ws_size,
                              hipStream_t stream) {
    const float* line    = (const float*)d_in[0];
    const float* pts     = (const float*)d_in[1];
    const float* gt      = (const float*)d_in[2];
    const float* table_c = (const float*)d_in[3];
    const float* w1_c    = (const float*)d_in[4];
    const float* b1_c    = (const float*)d_in[5];
    const float* w2_c    = (const float*)d_in[6];
    const float* b2_c    = (const float*)d_in[7];
    const float* table_o = (const float*)d_in[8];
    const float* w1_o    = (const float*)d_in[9];
    const float* b1_o    = (const float*)d_in[10];
    const float* w2_o    = (const float*)d_in[11];
    const float* b2_o    = (const float*)d_in[12];
    (void)in_sizes; (void)n_in; (void)out_size; (void)ws_size;

    Specs sp3, sp2;
    compute_specs(3, &sp3);
    compute_specs(2, &sp2);

    float* S       = (float*)d_ws;       // [4096]
    float* partial = S + B_LINES;        // [16]

    opacity_kernel<<<B_LINES, 256, 0, stream>>>(
        pts, gt, (const float2*)table_o, w1_o, b1_o, w2_o, b2_o, S, sp3);
    conf_kernel<<<16, 256, 0, stream>>>(
        line, (const float2*)table_c, w1_c, b1_c, w2_c, b2_c, S, partial, sp2);
    final_kernel<<<1, 64, 0, stream>>>(partial, (float*)d_out);
}